// Round 17
// baseline (111.048 us; speedup 1.0000x reference)
//
#include <hip/hip_runtime.h>
#include <hip/hip_bf16.h>

// Problem constants
#define TT   1024            // time steps
#define DD   1280            // feature dim
#define WW   320             // DD / POOL
#define CC   20              // channels
#define HALF 10
#define TW   (TT*WW)         // 327680
#define LIN  (CC*WW)         // 6400  (GEMM K)
#define OUTD 80              // GEMM N
#define NSPLIT 20            // split-K: 320 cols each
#define LOG2E 1.4426950408889634f
#define XPAD 384             // floats of guard on each side of x

#define POOL_BLOCKS (TW/256)             // 1280
#define CVT_BLOCKS  ((OUTD*LIN)/(256*8)) // 250
#define ZERO_BLOCKS ((TT*OUTD)/(256*4))  // 80

typedef __attribute__((ext_vector_type(4))) float f32x4;
typedef __attribute__((ext_vector_type(8))) short bf16x8;

// RNE float->bf16, finite values only (no NaN path)
__device__ __forceinline__ ushort f2bf(float v) {
    unsigned u = __float_as_uint(v);
    u += 0x7FFFu + ((u >> 16) & 1u);
    return (ushort)(u >> 16);
}

// pack two f32 -> two bf16 in one instruction
__device__ __forceinline__ unsigned pk_bf16(float lo, float hi) {
    unsigned r;
    asm("v_cvt_pk_bf16_f32 %0, %1, %2" : "=v"(r) : "v"(lo), "v"(hi));
    return r;
}

// ---- Kernel 1: MaxPool2d((1,4)) + dense_w fp32->bf16 (PERMUTED) + zero(out) ----
__global__ __launch_bounds__(256) void k_prep(const float* __restrict__ f,
                                              float* __restrict__ x,
                                              const float* __restrict__ dw,
                                              ushort* __restrict__ dwb,
                                              float* __restrict__ out) {
    int b = blockIdx.x;
    if (b < POOL_BLOCKS) {
        int idx = b * 256 + threadIdx.x;               // over TW, exact
        float4 v = reinterpret_cast<const float4*>(f)[idx];
        x[idx] = fmaxf(fmaxf(v.x, v.y), fmaxf(v.z, v.w));
    } else if (b < POOL_BLOCKS + CVT_BLOCKS) {
        int q = (b - POOL_BLOCKS) * 256 + threadIdx.x; // 0..63999 (8-elem units)
        int r16 = q & 15;
        int kg  = (q >> 4) & 3;
        int z   = q >> 6;          // (sp*10+ks)*5 + jj
        int jj  = z % 5;
        int y   = z / 5;           // sp*10 + ks
        int ks  = y % 10;
        int sp  = y / 10;
        const float* src = dw + (size_t)(jj * 16 + r16) * LIN + sp * 320 + ks * 32 + kg * 8;
        float4 a = reinterpret_cast<const float4*>(src)[0];
        float4 c = reinterpret_cast<const float4*>(src)[1];
        reinterpret_cast<ushort4*>(dwb + (size_t)q * 8)[0] =
            make_ushort4(f2bf(a.x), f2bf(a.y), f2bf(a.z), f2bf(a.w));
        reinterpret_cast<ushort4*>(dwb + (size_t)q * 8)[1] =
            make_ushort4(f2bf(c.x), f2bf(c.y), f2bf(c.z), f2bf(c.w));
    } else {
        int idx = (b - POOL_BLOCKS - CVT_BLOCKS) * 256 + threadIdx.x;  // over TT*OUTD/4
        reinterpret_cast<float4*>(out)[idx] = make_float4(0.f, 0.f, 0.f, 0.f);
    }
}

// ---------------- attention for one 4-wide w-group of one channel ----------------
template<bool ISH>
__device__ __forceinline__ uint2 attn_g(const float xr[3][6], float qk,
                                        float r0, float r1, float r2, float vv) {
    float o[4];
    #pragma unroll
    for (int p = 0; p < 4; ++p) {
        float xc = xr[1][p + 1];
        float a  = qk * xc;
        float bb0 = r0 * xc, bb1 = r1 * xc, bb2 = r2 * xc;
        float s[9];
        #pragma unroll
        for (int i = 0; i < 9; ++i) {
            int dt = i / 3, dw = i % 3;
            float bias = ISH ? ((dt == 0) ? bb0 : (dt == 1) ? bb1 : bb2)
                             : ((dw == 0) ? bb0 : (dw == 1) ? bb1 : bb2);
            s[i] = fmaf(a, xr[dt][p + dw], bias);
        }
        float m = fmaxf(fmaxf(fmaxf(fmaxf(s[0], s[1]), s[2]),
                              fmaxf(fmaxf(s[3], s[4]), s[5])),
                        fmaxf(fmaxf(s[6], s[7]), s[8]));
        float den0 = 0.f, den1 = 0.f, num0 = 0.f, num1 = 0.f;
        #pragma unroll
        for (int i = 0; i < 9; ++i) {
            float e = __builtin_amdgcn_exp2f(s[i] - m);
            if (i & 1) { den1 += e; num1 = fmaf(e, xr[i / 3][p + i % 3], num1); }
            else       { den0 += e; num0 = fmaf(e, xr[i / 3][p + i % 3], num0); }
        }
        float den = den0 + den1, num = num0 + num1;
        o[p] = fmaxf(vv * (num * __builtin_amdgcn_rcpf(den)), 0.0f);
    }
    return make_uint2(pk_bf16(o[0], o[1]), pk_bf16(o[2], o[3]));
}

// window loads for one u-group: 3 rows x (scalar, float4, scalar)
__device__ __forceinline__ void load_u(const float* __restrict__ xb0, int w0,
                                       float4 vb[3], float xm1[3], float xp4[3]) {
    #pragma unroll
    for (int dt = 0; dt < 3; ++dt) {
        const float* rpx = xb0 + (dt - 1) * WW + w0;
        xm1[dt] = rpx[-1];
        vb[dt]  = *reinterpret_cast<const float4*>(rpx);
        xp4[dt] = rpx[4];
    }
}

// ---------------- Kernel 2: FUSED attention + split-K MFMA GEMM -> atomic out ----------------
// MODE 0 = full; MODE 1 = attention-phase only (diagnostic, LDS kept live).
template<int MODE>
__global__ __launch_bounds__(256, 6) void k_fused(const float* __restrict__ x,
                                                  const float* __restrict__ wq,
                                                  const float* __restrict__ wk,
                                                  const float* __restrict__ wv,
                                                  const float* __restrict__ rh,
                                                  const float* __restrict__ rw,
                                                  const ushort* __restrict__ dwb,
                                                  const float* __restrict__ bias,
                                                  float* __restrict__ out) {
    __shared__ __align__(16) ushort alds[16][328];     // [row][w] bf16
    __shared__ float red[2][16][81];                   // two-stage cross-wave reduce

    int tid = threadIdx.x;
    int mt  = blockIdx.x;          // 0..63  A-row tile
    int sp  = blockIdx.y;          // 0..19  K-chunk
    out += (size_t)blockIdx.z * TT * OUTD;             // probe slabs (z=0 for real)

    // ---- Phase 1: attention, one channel per thread-row, pipelined window loads ----
    {
        int j  = tid >> 4;                 // local A-row 0..15
        int wg = tid & 15;                 // w-group 0..15 (x5 strided groups)
        int ct = (mt * 16 + j) * 20 + sp;  // c*1024 + t
        int t  = ct & 1023;
        int c  = ct >> 10;
        bool ish = (c < HALF);

        float wqc = wq[c];
        float qk  = wqc * wk[c] * LOG2E;
        float vv  = wv[c];
        const float* rp = ish ? (rh + c * 3) : (rw + (c - HALF) * 3);
        float r0 = wqc * rp[0] * LOG2E;
        float r1 = wqc * rp[1] * LOG2E;
        float r2 = wqc * rp[2] * LOG2E;

        bool rok0 = (t > 0), rok2 = (t < TT - 1);
        const float* xb0 = x + t * WW;

        float4 vbb[2][3];
        float  xm1b[2][3], xp4b[2][3];
        load_u(xb0, wg * 4, vbb[0], xm1b[0], xp4b[0]);

        #pragma unroll
        for (int u = 0; u < 5; ++u) {
            int cur = u & 1;
            if (u < 4)
                load_u(xb0, (wg + 16 * (u + 1)) * 4, vbb[cur ^ 1], xm1b[cur ^ 1], xp4b[cur ^ 1]);

            int gg = wg + 16 * u;          // global w-group 0..79
            int w0 = gg * 4;
            float xr[3][6];
            #pragma unroll
            for (int dt = 0; dt < 3; ++dt) {
                bool rok = (dt == 1) ? true : ((dt == 0) ? rok0 : rok2);
                xr[dt][0] = (rok & (gg > 0))  ? xm1b[cur][dt] : 0.f;
                xr[dt][1] = rok ? vbb[cur][dt].x : 0.f;
                xr[dt][2] = rok ? vbb[cur][dt].y : 0.f;
                xr[dt][3] = rok ? vbb[cur][dt].z : 0.f;
                xr[dt][4] = rok ? vbb[cur][dt].w : 0.f;
                xr[dt][5] = (rok & (gg < 79)) ? xp4b[cur][dt] : 0.f;
            }
            uint2 res = ish ? attn_g<true >(xr, qk, r0, r1, r2, vv)
                            : attn_g<false>(xr, qk, r0, r1, r2, vv);
            *reinterpret_cast<uint2*>(&alds[j][w0]) = res;
        }
    }

    __syncthreads();

    if constexpr (MODE == 1) {
        // keepalive: checksum a stride over alds so phase-1 stores can't be DCE'd
        float acc = 0.f;
        for (int i = tid; i < 16 * 328; i += 256)
            acc += (float)alds[i / 328][i % 328];
        if (acc == 12345.678f) out[tid] = acc;   // never true in practice; deterministic
        return;
    }

    // ---- Phase 2: MFMA 16x80 over the 320-col K-chunk (coalesced permuted B) ----
    int wave = tid >> 6;
    int lane = tid & 63;
    int r16  = lane & 15;          // A row / B out-col
    int kg   = lane >> 4;          // k-group 0..3

    int ks0 = (wave < 2) ? wave * 3 : 6 + (wave - 2) * 2;
    int ksn = (wave < 2) ? 3 : 2;

    f32x4 acc[5] = {};
    for (int ks = ks0; ks < ks0 + ksn; ++ks) {
        bf16x8 af = *reinterpret_cast<const bf16x8*>(&alds[r16][ks * 32 + kg * 8]);
        const ushort* bp = dwb + (size_t)(((sp * 10 + ks) * 5) * 64 + lane) * 8;
        #pragma unroll
        for (int jj = 0; jj < 5; ++jj) {
            bf16x8 bfr = *reinterpret_cast<const bf16x8*>(bp + (size_t)jj * 512);
            acc[jj] = __builtin_amdgcn_mfma_f32_16x16x32_bf16(af, bfr, acc[jj], 0, 0, 0);
        }
    }

    // ---- cross-wave reduce: waves 0/1 store, waves 2/3 accumulate, then sum 2 ----
    if (wave < 2) {
        #pragma unroll
        for (int jj = 0; jj < 5; ++jj)
            #pragma unroll
            for (int r = 0; r < 4; ++r)
                red[wave][kg * 4 + r][jj * 16 + r16] = acc[jj][r];
    }
    __syncthreads();
    if (wave >= 2) {
        #pragma unroll
        for (int jj = 0; jj < 5; ++jj)
            #pragma unroll
            for (int r = 0; r < 4; ++r)
                red[wave - 2][kg * 4 + r][jj * 16 + r16] += acc[jj][r];
    }
    __syncthreads();

    float* op = out + (size_t)(mt * 16) * OUTD;
    #pragma unroll
    for (int i2 = tid; i2 < 16 * 80; i2 += 256) {
        int row = i2 / 80, col = i2 % 80;
        float v = red[0][row][col] + red[1][row][col];
        if (sp == 0) v += bias[col];
        atomicAdd(&op[i2], v);
    }
}

extern "C" void kernel_launch(void* const* d_in, const int* in_sizes, int n_in,
                              void* d_out, int out_size, void* d_ws, size_t ws_size,
                              hipStream_t stream) {
    const float* feature = (const float*)d_in[0];
    const float* wq      = (const float*)d_in[1];
    const float* wk      = (const float*)d_in[2];
    const float* wv      = (const float*)d_in[3];
    const float* rel_h   = (const float*)d_in[4];
    const float* rel_w   = (const float*)d_in[5];
    const float* dense_w = (const float*)d_in[6];
    const float* dense_b = (const float*)d_in[7];
    float* out = (float*)d_out;

    float*  ws   = (float*)d_ws;
    float*  x    = ws + XPAD;                            // TW floats, guarded both sides
    ushort* dwb  = (ushort*)(ws + 2 * XPAD + TW);        // OUTD*LIN bf16 (permuted, 1.02 MB)
    float*  scrA = (float*)(dwb + (size_t)OUTD * LIN);   // 3 x TT*OUTD probe slabs
    float*  scrB = scrA + 3 * (size_t)TT * OUTD;         // 3 x TT*OUTD probe slabs

    k_prep <<<POOL_BLOCKS + CVT_BLOCKS + ZERO_BLOCKS, 256, 0, stream>>>(feature, x, dense_w,
                                                                        dwb, out);
    // PROBE A: full fused x3 (counters for the whole kernel)
    k_fused<0><<<dim3(TT/16, NSPLIT, 3), 256, 0, stream>>>(x, wq, wk, wv, rel_h, rel_w,
                                                           dwb, dense_b, scrA);
    // PROBE B: attention-phase only x3 (counters for phase 1 alone)
    k_fused<1><<<dim3(TT/16, NSPLIT, 3), 256, 0, stream>>>(x, wq, wk, wv, rel_h, rel_w,
                                                           dwb, dense_b, scrB);
    // REAL dispatch (unchanged R14 path)
    k_fused<0><<<dim3(TT/16, NSPLIT, 1), 256, 0, stream>>>(x, wq, wk, wv, rel_h, rel_w,
                                                           dwb, dense_b, out);
}

// Round 18
// 27.671 us; speedup vs baseline: 4.0131x; 4.0131x over previous
//
#include <hip/hip_runtime.h>
#include <hip/hip_bf16.h>

// Problem constants
#define TT   1024            // time steps
#define DD   1280            // feature dim
#define WW   320             // DD / POOL
#define CC   20              // channels
#define HALF 10
#define TW   (TT*WW)         // 327680
#define LIN  (CC*WW)         // 6400  (GEMM K)
#define OUTD 80              // GEMM N
#define NSPLIT 20            // split-K: 320 cols each
#define LOG2E 1.4426950408889634f

// padded pooled-map layout: rows -1..1024, 4 guard cols each side
#define PITCH 328
#define XOFF  4
#define XROWS 1026
#define XSZ   (XROWS*PITCH)              // 336528 floats

#define POOL_BLOCKS (TW/256)             // 1280
#define CVT_BLOCKS  ((OUTD*LIN)/(256*8)) // 250
#define ZERO_BLOCKS ((TT*OUTD)/(256*4))  // 80
#define GUARD_N     (2*PITCH + 1024*8)   // 8848 guard cells
#define GUARD_BLOCKS ((GUARD_N+255)/256) // 35

typedef __attribute__((ext_vector_type(4))) float f32x4;
typedef __attribute__((ext_vector_type(8))) short bf16x8;

// RNE float->bf16, finite values only (no NaN path)
__device__ __forceinline__ ushort f2bf(float v) {
    unsigned u = __float_as_uint(v);
    u += 0x7FFFu + ((u >> 16) & 1u);
    return (ushort)(u >> 16);
}

// pack two f32 -> two bf16 in one instruction
__device__ __forceinline__ unsigned pk_bf16(float lo, float hi) {
    unsigned r;
    asm("v_cvt_pk_bf16_f32 %0, %1, %2" : "=v"(r) : "v"(lo), "v"(hi));
    return r;
}

// ---- Kernel 1: pool (padded layout) + dense_w cvt (PERMUTED) + zero(out) + zero(guards) ----
__global__ __launch_bounds__(256) void k_prep(const float* __restrict__ f,
                                              float* __restrict__ xg,
                                              const float* __restrict__ dw,
                                              ushort* __restrict__ dwb,
                                              float* __restrict__ out) {
    int b = blockIdx.x;
    if (b < POOL_BLOCKS) {
        int idx = b * 256 + threadIdx.x;               // over TW, exact
        float4 v = reinterpret_cast<const float4*>(f)[idx];
        int t = idx / WW, w = idx % WW;
        xg[(t + 1) * PITCH + XOFF + w] = fmaxf(fmaxf(v.x, v.y), fmaxf(v.z, v.w));
    } else if (b < POOL_BLOCKS + CVT_BLOCKS) {
        int q = (b - POOL_BLOCKS) * 256 + threadIdx.x; // 0..63999 (8-elem units)
        int r16 = q & 15;
        int kg  = (q >> 4) & 3;
        int z   = q >> 6;          // (sp*10+ks)*5 + jj
        int jj  = z % 5;
        int y   = z / 5;           // sp*10 + ks
        int ks  = y % 10;
        int sp  = y / 10;
        const float* src = dw + (size_t)(jj * 16 + r16) * LIN + sp * 320 + ks * 32 + kg * 8;
        float4 a = reinterpret_cast<const float4*>(src)[0];
        float4 c = reinterpret_cast<const float4*>(src)[1];
        reinterpret_cast<ushort4*>(dwb + (size_t)q * 8)[0] =
            make_ushort4(f2bf(a.x), f2bf(a.y), f2bf(a.z), f2bf(a.w));
        reinterpret_cast<ushort4*>(dwb + (size_t)q * 8)[1] =
            make_ushort4(f2bf(c.x), f2bf(c.y), f2bf(c.z), f2bf(c.w));
    } else if (b < POOL_BLOCKS + CVT_BLOCKS + ZERO_BLOCKS) {
        int idx = (b - POOL_BLOCKS - CVT_BLOCKS) * 256 + threadIdx.x;  // over TT*OUTD/4
        reinterpret_cast<float4*>(out)[idx] = make_float4(0.f, 0.f, 0.f, 0.f);
    } else {
        int i = (b - POOL_BLOCKS - CVT_BLOCKS - ZERO_BLOCKS) * 256 + threadIdx.x;
        if (i < GUARD_N) {
            int off;
            if (i < PITCH)            off = i;                              // top guard row
            else if (i < 2 * PITCH)   off = 1025 * PITCH + (i - PITCH);     // bottom guard row
            else {
                int j = i - 2 * PITCH;
                int r = j >> 3, cp = j & 7;
                off = (r + 1) * PITCH + ((cp < 4) ? cp : (320 + cp));       // 0..3 / 324..327
            }
            xg[off] = 0.f;
        }
    }
}

// ---------------- attention for one 4-wide w-group of one channel ----------------
// s[i] = fmaf(a, xr[dt][p+dw], bb_sel), a = qk*xc, bb = r*xc. No boundary logic:
// halo zeros come from the padded buffer.
template<bool ISH>
__device__ __forceinline__ uint2 attn_g(const float xr[3][6], float qk,
                                        float r0, float r1, float r2, float vv) {
    float o[4];
    #pragma unroll
    for (int p = 0; p < 4; ++p) {
        float xc = xr[1][p + 1];
        float a  = qk * xc;
        float bb0 = r0 * xc, bb1 = r1 * xc, bb2 = r2 * xc;
        float s[9];
        #pragma unroll
        for (int i = 0; i < 9; ++i) {
            int dt = i / 3, dw = i % 3;
            float bias = ISH ? ((dt == 0) ? bb0 : (dt == 1) ? bb1 : bb2)
                             : ((dw == 0) ? bb0 : (dw == 1) ? bb1 : bb2);
            s[i] = fmaf(a, xr[dt][p + dw], bias);
        }
        float m = fmaxf(fmaxf(fmaxf(fmaxf(s[0], s[1]), s[2]),
                              fmaxf(fmaxf(s[3], s[4]), s[5])),
                        fmaxf(fmaxf(s[6], s[7]), s[8]));
        float den0 = 0.f, den1 = 0.f, num0 = 0.f, num1 = 0.f;
        #pragma unroll
        for (int i = 0; i < 9; ++i) {
            float e = __builtin_amdgcn_exp2f(s[i] - m);
            if (i & 1) { den1 += e; num1 = fmaf(e, xr[i / 3][p + i % 3], num1); }
            else       { den0 += e; num0 = fmaf(e, xr[i / 3][p + i % 3], num0); }
        }
        float den = den0 + den1, num = num0 + num1;
        o[p] = fmaxf(vv * (num * __builtin_amdgcn_rcpf(den)), 0.0f);
    }
    return make_uint2(pk_bf16(o[0], o[1]), pk_bf16(o[2], o[3]));
}

// ---------------- Kernel 2: FUSED attention + split-K MFMA GEMM -> atomic out ----------------
// Flatten semantics: GEMM A-row r, col k = att linear element r*6400 + k,
// i.e. with k = sp*320 + w:  c*1024 + t = r*20 + sp.
__global__ __launch_bounds__(256, 6) void k_fused(const float* __restrict__ xg,
                                                  const float* __restrict__ wq,
                                                  const float* __restrict__ wk,
                                                  const float* __restrict__ wv,
                                                  const float* __restrict__ rh,
                                                  const float* __restrict__ rw,
                                                  const ushort* __restrict__ dwb,
                                                  const float* __restrict__ bias,
                                                  float* __restrict__ out) {
    __shared__ __align__(16) ushort alds[16][328];     // [row][w] bf16
    __shared__ float red[2][16][81];                   // two-stage cross-wave reduce

    int tid = threadIdx.x;
    int mt  = blockIdx.x;          // 0..63  A-row tile
    int sp  = blockIdx.y;          // 0..19  K-chunk

    // ---- Phase 1: attention, one channel per thread-row, unconditional window loads ----
    {
        int j  = tid >> 4;                 // local A-row 0..15
        int wg = tid & 15;                 // w-group 0..15 (x5 strided groups)
        int ct = (mt * 16 + j) * 20 + sp;  // c*1024 + t
        int t  = ct & 1023;
        int c  = ct >> 10;
        bool ish = (c < HALF);

        float wqc = wq[c];
        float qk  = wqc * wk[c] * LOG2E;
        float vv  = wv[c];
        const float* rp = ish ? (rh + c * 3) : (rw + (c - HALF) * 3);
        float r0 = wqc * rp[0] * LOG2E;
        float r1 = wqc * rp[1] * LOG2E;
        float r2 = wqc * rp[2] * LOG2E;

        const float* xb0 = xg + (t + 1) * PITCH + XOFF;

        for (int u = 0; u < 5; ++u) {
            int w0 = (wg + 16 * u) * 4;    // 0..316
            float xr[3][6];
            #pragma unroll
            for (int dt = 0; dt < 3; ++dt) {
                const float* rpx = xb0 + (dt - 1) * PITCH + w0;
                float4 vb = *reinterpret_cast<const float4*>(rpx);
                xr[dt][0] = rpx[-1];
                xr[dt][1] = vb.x; xr[dt][2] = vb.y;
                xr[dt][3] = vb.z; xr[dt][4] = vb.w;
                xr[dt][5] = rpx[4];
            }
            uint2 res = ish ? attn_g<true >(xr, qk, r0, r1, r2, vv)
                            : attn_g<false>(xr, qk, r0, r1, r2, vv);
            *reinterpret_cast<uint2*>(&alds[j][w0]) = res;
        }
    }

    __syncthreads();

    // ---- Phase 2: MFMA 16x80 over the 320-col K-chunk (coalesced permuted B) ----
    int wave = tid >> 6;
    int lane = tid & 63;
    int r16  = lane & 15;          // A row / B out-col
    int kg   = lane >> 4;          // k-group 0..3

    int ks0 = (wave < 2) ? wave * 3 : 6 + (wave - 2) * 2;
    int ksn = (wave < 2) ? 3 : 2;

    f32x4 acc[5] = {};
    for (int ks = ks0; ks < ks0 + ksn; ++ks) {
        bf16x8 af = *reinterpret_cast<const bf16x8*>(&alds[r16][ks * 32 + kg * 8]);
        const ushort* bp = dwb + (size_t)(((sp * 10 + ks) * 5) * 64 + lane) * 8;
        #pragma unroll
        for (int jj = 0; jj < 5; ++jj) {
            bf16x8 bfr = *reinterpret_cast<const bf16x8*>(bp + (size_t)jj * 512);
            acc[jj] = __builtin_amdgcn_mfma_f32_16x16x32_bf16(af, bfr, acc[jj], 0, 0, 0);
        }
    }

    // ---- cross-wave reduce: waves 0/1 store, waves 2/3 accumulate, then sum 2 ----
    // C/D layout: col = lane&15, row = kg*4 + reg
    if (wave < 2) {
        #pragma unroll
        for (int jj = 0; jj < 5; ++jj)
            #pragma unroll
            for (int r = 0; r < 4; ++r)
                red[wave][kg * 4 + r][jj * 16 + r16] = acc[jj][r];
    }
    __syncthreads();
    if (wave >= 2) {
        #pragma unroll
        for (int jj = 0; jj < 5; ++jj)
            #pragma unroll
            for (int r = 0; r < 4; ++r)
                red[wave - 2][kg * 4 + r][jj * 16 + r16] += acc[jj][r];
    }
    __syncthreads();

    float* op = out + (size_t)(mt * 16) * OUTD;
    #pragma unroll
    for (int i2 = tid; i2 < 16 * 80; i2 += 256) {
        int row = i2 / 80, col = i2 % 80;
        float v = red[0][row][col] + red[1][row][col];
        if (sp == 0) v += bias[col];
        atomicAdd(&op[i2], v);
    }
}

extern "C" void kernel_launch(void* const* d_in, const int* in_sizes, int n_in,
                              void* d_out, int out_size, void* d_ws, size_t ws_size,
                              hipStream_t stream) {
    const float* feature = (const float*)d_in[0];
    const float* wq      = (const float*)d_in[1];
    const float* wk      = (const float*)d_in[2];
    const float* wv      = (const float*)d_in[3];
    const float* rel_h   = (const float*)d_in[4];
    const float* rel_w   = (const float*)d_in[5];
    const float* dense_w = (const float*)d_in[6];
    const float* dense_b = (const float*)d_in[7];
    float* out = (float*)d_out;

    float*  ws  = (float*)d_ws;
    float*  xg  = ws;                                    // padded pooled map (1.35 MB)
    ushort* dwb = (ushort*)(ws + XSZ);                   // OUTD*LIN bf16 (permuted, 1.02 MB)

    k_prep <<<POOL_BLOCKS + CVT_BLOCKS + ZERO_BLOCKS + GUARD_BLOCKS, 256, 0, stream>>>(
        feature, xg, dense_w, dwb, out);
    k_fused<<<dim3(TT/16, NSPLIT), 256, 0, stream>>>(xg, wq, wk, wv, rel_h, rel_w,
                                                     dwb, dense_b, out);
}

// Round 19
// 26.761 us; speedup vs baseline: 4.1496x; 1.0340x over previous
//
#include <hip/hip_runtime.h>
#include <hip/hip_bf16.h>

// Problem constants
#define TT   1024            // time steps
#define DD   1280            // feature dim
#define WW   320             // DD / POOL
#define CC   20              // channels
#define HALF 10
#define TW   (TT*WW)         // 327680
#define LIN  (CC*WW)         // 6400  (GEMM K)
#define OUTD 80              // GEMM N
#define NSPLIT 20            // split-K: 320 cols each
#define LOG2E 1.4426950408889634f

// padded pooled-map layout: rows -1..1024, 4 guard cols each side
#define PITCH 328
#define XOFF  4
#define XROWS 1026
#define XSZ   (XROWS*PITCH)              // 336528 floats

#define POOL_BLOCKS (TW/256)             // 1280
#define CVT_BLOCKS  ((OUTD*LIN)/(256*8)) // 250
#define ZERO_BLOCKS ((TT*OUTD)/(256*4))  // 80
#define GUARD_N     (2*PITCH + 1024*8)   // 8848 guard cells
#define GUARD_BLOCKS ((GUARD_N+255)/256) // 35

typedef __attribute__((ext_vector_type(2))) float f32x2;
typedef __attribute__((ext_vector_type(4))) float f32x4;
typedef __attribute__((ext_vector_type(8))) short bf16x8;

// RNE float->bf16, finite values only (no NaN path)
__device__ __forceinline__ ushort f2bf(float v) {
    unsigned u = __float_as_uint(v);
    u += 0x7FFFu + ((u >> 16) & 1u);
    return (ushort)(u >> 16);
}

// pack two f32 -> two bf16 in one instruction
__device__ __forceinline__ unsigned pk_bf16(float lo, float hi) {
    unsigned r;
    asm("v_cvt_pk_bf16_f32 %0, %1, %2" : "=v"(r) : "v"(lo), "v"(hi));
    return r;
}

__device__ __forceinline__ f32x2 vmax2(f32x2 a, f32x2 b) {
    return __builtin_elementwise_max(a, b);
}

// ---- Kernel 1: pool (padded layout) + dense_w cvt (PERMUTED) + zero(out) + zero(guards) ----
__global__ __launch_bounds__(256) void k_prep(const float* __restrict__ f,
                                              float* __restrict__ xg,
                                              const float* __restrict__ dw,
                                              ushort* __restrict__ dwb,
                                              float* __restrict__ out) {
    int b = blockIdx.x;
    if (b < POOL_BLOCKS) {
        int idx = b * 256 + threadIdx.x;               // over TW, exact
        float4 v = reinterpret_cast<const float4*>(f)[idx];
        int t = idx / WW, w = idx % WW;
        xg[(t + 1) * PITCH + XOFF + w] = fmaxf(fmaxf(v.x, v.y), fmaxf(v.z, v.w));
    } else if (b < POOL_BLOCKS + CVT_BLOCKS) {
        int q = (b - POOL_BLOCKS) * 256 + threadIdx.x; // 0..63999 (8-elem units)
        int r16 = q & 15;
        int kg  = (q >> 4) & 3;
        int z   = q >> 6;          // (sp*10+ks)*5 + jj
        int jj  = z % 5;
        int y   = z / 5;           // sp*10 + ks
        int ks  = y % 10;
        int sp  = y / 10;
        const float* src = dw + (size_t)(jj * 16 + r16) * LIN + sp * 320 + ks * 32 + kg * 8;
        float4 a = reinterpret_cast<const float4*>(src)[0];
        float4 c = reinterpret_cast<const float4*>(src)[1];
        reinterpret_cast<ushort4*>(dwb + (size_t)q * 8)[0] =
            make_ushort4(f2bf(a.x), f2bf(a.y), f2bf(a.z), f2bf(a.w));
        reinterpret_cast<ushort4*>(dwb + (size_t)q * 8)[1] =
            make_ushort4(f2bf(c.x), f2bf(c.y), f2bf(c.z), f2bf(c.w));
    } else if (b < POOL_BLOCKS + CVT_BLOCKS + ZERO_BLOCKS) {
        int idx = (b - POOL_BLOCKS - CVT_BLOCKS) * 256 + threadIdx.x;  // over TT*OUTD/4
        reinterpret_cast<float4*>(out)[idx] = make_float4(0.f, 0.f, 0.f, 0.f);
    } else {
        int i = (b - POOL_BLOCKS - CVT_BLOCKS - ZERO_BLOCKS) * 256 + threadIdx.x;
        if (i < GUARD_N) {
            int off;
            if (i < PITCH)            off = i;                              // top guard row
            else if (i < 2 * PITCH)   off = 1025 * PITCH + (i - PITCH);     // bottom guard row
            else {
                int j = i - 2 * PITCH;
                int r = j >> 3, cp = j & 7;
                off = (r + 1) * PITCH + ((cp < 4) ? cp : (320 + cp));       // 0..3 / 324..327
            }
            xg[off] = 0.f;
        }
    }
}

// ---------------- attention for one 4-wide w-group of one channel, PACKED f32x2 ----------------
// Positions p and p+1 processed as vector lanes; all score/softmax arithmetic
// lowers to v_pk_{fma,mul,add,max}_f32. exp/rcp remain scalar (trans pipe).
template<bool ISH>
__device__ __forceinline__ uint2 attn_g(const float xr[3][6], float qk,
                                        float r0, float r1, float r2, float vv) {
    unsigned res[2];
    #pragma unroll
    for (int pp = 0; pp < 2; ++pp) {
        int p0 = pp * 2;
        f32x2 xc = {xr[1][p0 + 1], xr[1][p0 + 2]};
        f32x2 a   = qk * xc;
        f32x2 bb0 = r0 * xc, bb1 = r1 * xc, bb2 = r2 * xc;
        f32x2 xv[9], s[9];
        #pragma unroll
        for (int i = 0; i < 9; ++i) {
            int dt = i / 3, dw = i % 3;
            xv[i] = f32x2{xr[dt][p0 + dw], xr[dt][p0 + dw + 1]};
            f32x2 bias = ISH ? ((dt == 0) ? bb0 : (dt == 1) ? bb1 : bb2)
                             : ((dw == 0) ? bb0 : (dw == 1) ? bb1 : bb2);
            s[i] = a * xv[i] + bias;
        }
        f32x2 m = vmax2(vmax2(vmax2(vmax2(s[0], s[1]), s[2]),
                              vmax2(vmax2(s[3], s[4]), s[5])),
                        vmax2(vmax2(s[6], s[7]), s[8]));
        f32x2 den = {0.f, 0.f}, num = {0.f, 0.f};
        #pragma unroll
        for (int i = 0; i < 9; ++i) {
            f32x2 d = s[i] - m;
            f32x2 e = {__builtin_amdgcn_exp2f(d.x), __builtin_amdgcn_exp2f(d.y)};
            den += e;
            num += e * xv[i];
        }
        float o0 = fmaxf(vv * (num.x * __builtin_amdgcn_rcpf(den.x)), 0.0f);
        float o1 = fmaxf(vv * (num.y * __builtin_amdgcn_rcpf(den.y)), 0.0f);
        res[pp] = pk_bf16(o0, o1);
    }
    return make_uint2(res[0], res[1]);
}

// ---------------- Kernel 2: FUSED attention + split-K MFMA GEMM -> atomic out ----------------
// Flatten semantics: GEMM A-row r, col k = att linear element r*6400 + k,
// i.e. with k = sp*320 + w:  c*1024 + t = r*20 + sp.
__global__ __launch_bounds__(256, 6) void k_fused(const float* __restrict__ xg,
                                                  const float* __restrict__ wq,
                                                  const float* __restrict__ wk,
                                                  const float* __restrict__ wv,
                                                  const float* __restrict__ rh,
                                                  const float* __restrict__ rw,
                                                  const ushort* __restrict__ dwb,
                                                  const float* __restrict__ bias,
                                                  float* __restrict__ out) {
    __shared__ __align__(16) ushort alds[16][328];     // [row][w] bf16
    __shared__ float red[2][16][81];                   // two-stage cross-wave reduce

    int tid = threadIdx.x;
    int mt  = blockIdx.x;          // 0..63  A-row tile
    int sp  = blockIdx.y;          // 0..19  K-chunk

    // ---- Phase 1: attention, one channel per thread-row, unconditional window loads ----
    {
        int j  = tid >> 4;                 // local A-row 0..15
        int wg = tid & 15;                 // w-group 0..15 (x5 strided groups)
        int ct = (mt * 16 + j) * 20 + sp;  // c*1024 + t
        int t  = ct & 1023;
        int c  = ct >> 10;
        bool ish = (c < HALF);

        float wqc = wq[c];
        float qk  = wqc * wk[c] * LOG2E;
        float vv  = wv[c];
        const float* rp = ish ? (rh + c * 3) : (rw + (c - HALF) * 3);
        float r0 = wqc * rp[0] * LOG2E;
        float r1 = wqc * rp[1] * LOG2E;
        float r2 = wqc * rp[2] * LOG2E;

        const float* xb0 = xg + (t + 1) * PITCH + XOFF;

        for (int u = 0; u < 5; ++u) {
            int w0 = (wg + 16 * u) * 4;    // 0..316
            float xr[3][6];
            #pragma unroll
            for (int dt = 0; dt < 3; ++dt) {
                const float* rpx = xb0 + (dt - 1) * PITCH + w0;
                float4 vb = *reinterpret_cast<const float4*>(rpx);
                xr[dt][0] = rpx[-1];
                xr[dt][1] = vb.x; xr[dt][2] = vb.y;
                xr[dt][3] = vb.z; xr[dt][4] = vb.w;
                xr[dt][5] = rpx[4];
            }
            uint2 res = ish ? attn_g<true >(xr, qk, r0, r1, r2, vv)
                            : attn_g<false>(xr, qk, r0, r1, r2, vv);
            *reinterpret_cast<uint2*>(&alds[j][w0]) = res;
        }
    }

    __syncthreads();

    // ---- Phase 2: MFMA 16x80 over the 320-col K-chunk (coalesced permuted B) ----
    int wave = tid >> 6;
    int lane = tid & 63;
    int r16  = lane & 15;          // A row / B out-col
    int kg   = lane >> 4;          // k-group 0..3

    int ks0 = (wave < 2) ? wave * 3 : 6 + (wave - 2) * 2;
    int ksn = (wave < 2) ? 3 : 2;

    f32x4 acc[5] = {};
    for (int ks = ks0; ks < ks0 + ksn; ++ks) {
        bf16x8 af = *reinterpret_cast<const bf16x8*>(&alds[r16][ks * 32 + kg * 8]);
        const ushort* bp = dwb + (size_t)(((sp * 10 + ks) * 5) * 64 + lane) * 8;
        #pragma unroll
        for (int jj = 0; jj < 5; ++jj) {
            bf16x8 bfr = *reinterpret_cast<const bf16x8*>(bp + (size_t)jj * 512);
            acc[jj] = __builtin_amdgcn_mfma_f32_16x16x32_bf16(af, bfr, acc[jj], 0, 0, 0);
        }
    }

    // ---- cross-wave reduce: waves 0/1 store, waves 2/3 accumulate, then sum 2 ----
    // C/D layout: col = lane&15, row = kg*4 + reg
    if (wave < 2) {
        #pragma unroll
        for (int jj = 0; jj < 5; ++jj)
            #pragma unroll
            for (int r = 0; r < 4; ++r)
                red[wave][kg * 4 + r][jj * 16 + r16] = acc[jj][r];
    }
    __syncthreads();
    if (wave >= 2) {
        #pragma unroll
        for (int jj = 0; jj < 5; ++jj)
            #pragma unroll
            for (int r = 0; r < 4; ++r)
                red[wave - 2][kg * 4 + r][jj * 16 + r16] += acc[jj][r];
    }
    __syncthreads();

    float* op = out + (size_t)(mt * 16) * OUTD;
    #pragma unroll
    for (int i2 = tid; i2 < 16 * 80; i2 += 256) {
        int row = i2 / 80, col = i2 % 80;
        float v = red[0][row][col] + red[1][row][col];
        if (sp == 0) v += bias[col];
        atomicAdd(&op[i2], v);
    }
}

extern "C" void kernel_launch(void* const* d_in, const int* in_sizes, int n_in,
                              void* d_out, int out_size, void* d_ws, size_t ws_size,
                              hipStream_t stream) {
    const float* feature = (const float*)d_in[0];
    const float* wq      = (const float*)d_in[1];
    const float* wk      = (const float*)d_in[2];
    const float* wv      = (const float*)d_in[3];
    const float* rel_h   = (const float*)d_in[4];
    const float* rel_w   = (const float*)d_in[5];
    const float* dense_w = (const float*)d_in[6];
    const float* dense_b = (const float*)d_in[7];
    float* out = (float*)d_out;

    float*  ws  = (float*)d_ws;
    float*  xg  = ws;                                    // padded pooled map (1.35 MB)
    ushort* dwb = (ushort*)(ws + XSZ);                   // OUTD*LIN bf16 (permuted, 1.02 MB)

    k_prep <<<POOL_BLOCKS + CVT_BLOCKS + ZERO_BLOCKS + GUARD_BLOCKS, 256, 0, stream>>>(
        feature, xg, dense_w, dwb, out);
    k_fused<<<dim3(TT/16, NSPLIT), 256, 0, stream>>>(xg, wq, wk, wv, rel_h, rel_w,
                                                     dwb, dense_b, out);
}